// Round 5
// baseline (107.192 us; speedup 1.0000x reference)
//
#include <hip/hip_runtime.h>
#include <hip/hip_fp16.h>
#include <stdint.h>

// ---------------------------------------------------------------------------
// BareKANLayer: out[b,o] = sum_d PCHIP_interp(x[b,d]; coeffs[o,d,:]) + bias[o]
// B=8192, O=64, D=64, K=64, grid [-2,2], h = 4/63.
//
// Table: per (d, interval i, o) cubic coeffs of p(u) = c0 + c1 u + c2 u^2 + c3 u^3
// packed as fp16 in a uint2: .x = (h(c1)<<16)|h(c0), .y = (h(c3)<<16)|h(c2).
// Row i=63 is a LINEAR row for right extrapolation. Left extrap = row 0, w2=w3=0.
// Layout: T[d][i][o], slice per d = 64*64*8 = 32 KB, total 2 MB in d_ws.
//
// Round-5: LDS staging with R2/R3's failure causes removed.
//   R4 analysis: gather main is pinned at ~4.4 cy per L1 line-miss x 4.19M
//   lines (268 MB random rows, 0% L1 hit). Staging shrinks the traffic to
//   128 MB sequential, and serves the random access from LDS.
//   R3 failed on occupancy (2 waves/SIMD) + per-(b,d) REC reads. Fixes:
//   - 1024-thread blocks, LDS = 2x32KB dbuf only -> 2 blocks/CU, 8 waves/SIMD
//   - records in VGPRs (1 per lane), broadcast via v_readlane (SGPR, free)
//   - block = 128 b x 8 d; 512 blocks; 8 atomic contributions per out elem;
//     bias-init of out folded into build_table (R3-proven).
// ---------------------------------------------------------------------------

typedef _Float16 half2v __attribute__((ext_vector_type(2)));

#if defined(__has_builtin)
#if __has_builtin(__builtin_amdgcn_fdot2)
#define HAS_FDOT2 1
#endif
#endif

__device__ __forceinline__ uint32_t h16(float f) {
    return (uint32_t)__half_as_ushort(__float2half(f));   // RNE cvt
}

__device__ __forceinline__ float dot2acc(uint32_t a_bits, uint32_t b_bits, float acc) {
    half2v a = __builtin_bit_cast(half2v, a_bits);
    half2v b = __builtin_bit_cast(half2v, b_bits);
#ifdef HAS_FDOT2
    return __builtin_amdgcn_fdot2(a, b, acc, false);
#else
    return acc + (float)a.x * (float)b.x + (float)a.y * (float)b.y;
#endif
}

// Grid: 256 blocks (d = bx>>2, o-quarter = bx&3), 256 threads.
// Table build + bias-init of out (runs before kan_main on the stream).
__global__ void build_table(const float* __restrict__ coeffs, uint2* __restrict__ T,
                            const float* __restrict__ bias, float* __restrict__ out) {
    const float hf = 4.0f / 63.0f;
    const float inv_hf = 63.0f / 4.0f;   // 15.75 exact in fp32
    int d  = blockIdx.x >> 2;
    int ob = (blockIdx.x & 3) << 4;      // base of this block's 16 o's
    __shared__ float Y[16][65];          // +1 pad: conflict-free
    int t = threadIdx.x;
    {
        int ol = t >> 4;                 // 0..15  (o local)
        int k4 = (t & 15) << 2;          // 0,4,...,60
        const float* src = coeffs + (size_t)(ob + ol) * 4096 + d * 64 + k4;
        float4 v = *(const float4*)src;  // 16B aligned
        Y[ol][k4 + 0] = v.x; Y[ol][k4 + 1] = v.y;
        Y[ol][k4 + 2] = v.z; Y[ol][k4 + 3] = v.w;
    }
    // ---- bias-init out: 2048 floats per block, coalesced ----
    {
        float bv = bias[t & 63];
        int g = blockIdx.x * 2048 + t;
        #pragma unroll
        for (int i = 0; i < 8; ++i) out[g + i * 256] = bv;
    }
    __syncthreads();
    for (int c = t; c < 1024; c += 256) {
        int ol = c & 15;
        int i  = c >> 4;                 // 0..63 (63 = linear extrapolation row)
        const float* Yr = Y[ol];
        auto delt = [&](int k) -> float { return (Yr[k + 1] - Yr[k]) * inv_hf; };
        auto endslope = [&](float a, float b) -> float {
            float de = (3.0f * a - b) * 0.5f;
            de = (de * a <= 0.0f) ? 0.0f : de;
            de = ((a * b < 0.0f) && (fabsf(de) > 3.0f * fabsf(a))) ? 3.0f * a : de;
            return de;
        };
        auto slope = [&](int k) -> float {
            if (k == 0)  return endslope(delt(0), delt(1));
            if (k == 63) return endslope(delt(62), delt(61));
            float dp = delt(k - 1), dn = delt(k);
            return (dp * dn > 0.0f) ? (2.0f * dp * dn) / (dp + dn + 1e-12f) : 0.0f;
        };
        uint2 pk;
        if (i < 63) {
            float y0 = Yr[i], y1 = Yr[i + 1];
            float di = slope(i), dj = slope(i + 1);
            float c0 = y0;
            float c1 = hf * di;
            float c2 = 3.0f * (y1 - y0) - hf * (2.0f * di + dj);
            float c3 = 2.0f * (y0 - y1) + hf * (di + dj);
            pk.x = (h16(c1) << 16) | h16(c0);
            pk.y = (h16(c3) << 16) | h16(c2);
        } else {
            float yN = Yr[63];
            float dN = slope(63);
            pk.x = (h16(hf * dN) << 16) | h16(yN);
            pk.y = 0u;
        }
        T[(size_t)d * 4096 + i * 64 + (ob + ol)] = pk;
    }
}

// Grid: 512 blocks x 1024 threads (16 waves). Block: group = bx&7 -> d-range
// [8g, 8g+8); btile = bx>>3 -> 128 b's. Wave wv owns b's [btile*128 + wv*8, +8).
// Lane l holds the record for (b = wb + (l&7), d = dg + (l>>3)); broadcast via
// v_readlane. d-slices (32 KB) double-buffered in LDS; lane = o on reads.
__global__ void __launch_bounds__(1024, 8) kan_main(const float* __restrict__ x,
                                                    const char* __restrict__ Tb,
                                                    float* __restrict__ out) {
    __shared__ char BUF[2][32768];       // d-slice double buffer

    const int t     = threadIdx.x;
    const int lane  = t & 63;
    const int wv    = t >> 6;            // 0..15
    const int group = blockIdx.x & 7;    // d-group
    const int btile = blockIdx.x >> 3;   // 0..63
    const int dg    = group << 3;        // first d of group
    const int bw    = (btile << 7) + (wv << 3);   // wave's first b

    // ---- record for (b = bw + (lane&7), d = dg + (lane>>3)), in VGPRs ----
    uint32_t wa_bits, wb_bits, off_bits;
    {
        float xv = x[(bw + (lane & 7)) * 64 + dg + (lane >> 3)];
        float tt = (xv + 2.0f) * 15.75f;
        int i = (int)floorf(tt);
        i = i < 0 ? 0 : (i > 62 ? 62 : i);
        float u = tt - (float)i;
        float w1, w2, w3; uint32_t off;
        if (xv < -2.0f)      { w1 = tt;          w2 = 0.f;    w3 = 0.f;     off = 0u; }
        else if (xv > 2.0f)  { w1 = tt - 63.0f;  w2 = 0.f;    w3 = 0.f;     off = 63u << 9; }
        else                 { w1 = u;           w2 = u * u;  w3 = w2 * u;  off = (uint32_t)i << 9; }
        half2v wa; wa.x = (_Float16)1.0f; wa.y = (_Float16)w1;
        half2v wb; wb.x = (_Float16)w2;   wb.y = (_Float16)w3;
        wa_bits  = __builtin_bit_cast(uint32_t, wa);
        wb_bits  = __builtin_bit_cast(uint32_t, wb);
        off_bits = off;                  // i*512 within a slice
    }

    // ---- stage chunk 0 (d = dg) into BUF[0]: 1024 thr x 32 B ----
    {
        const char* src = Tb + ((size_t)dg << 15);
        #pragma unroll
        for (int r = 0; r < 2; ++r) {
            __builtin_amdgcn_global_load_lds(
                (const uint32_t*)(src + t * 16 + r * 16384),
                (uint32_t*)(&BUF[0][0] + t * 16 + r * 16384), 16, 0, 0);
        }
    }
    __syncthreads();                     // chunk 0 staged (vmcnt(0) drained)

    float acc[8];
    #pragma unroll
    for (int j = 0; j < 8; ++j) acc[j] = 0.0f;

    const int laneoff = lane << 3;
    for (int c = 0; c < 8; ++c) {        // 8 chunks x 1 d, double-buffered
        if (c < 7) {                     // issue next stage BEFORE compute
            const char* src = Tb + ((size_t)(dg + c + 1) << 15);
            char* dst = &BUF[(c + 1) & 1][0];
            #pragma unroll
            for (int r = 0; r < 2; ++r) {
                __builtin_amdgcn_global_load_lds(
                    (const uint32_t*)(src + t * 16 + r * 16384),
                    (uint32_t*)(dst + t * 16 + r * 16384), 16, 0, 0);
            }
        }
        const char* bufc = &BUF[c & 1][0];
        int cl = c << 3;
        #pragma unroll
        for (int j = 0; j < 8; ++j) {    // this wave's 8 b's
            uint32_t qa  = (uint32_t)__builtin_amdgcn_readlane((int)wa_bits,  cl + j);
            uint32_t qb  = (uint32_t)__builtin_amdgcn_readlane((int)wb_bits,  cl + j);
            uint32_t off = (uint32_t)__builtin_amdgcn_readlane((int)off_bits, cl + j);
            uint2 q = *(const uint2*)(bufc + off + laneoff);   // lane = o, 2-way free
            acc[j] = dot2acc(qa, q.x, acc[j]);
            acc[j] = dot2acc(qb, q.y, acc[j]);
        }
        __syncthreads();                 // next chunk staged; buffer swap safe
    }

    // ---- accumulate this d-group's partial into out (bias pre-initialized) ----
    #pragma unroll
    for (int j = 0; j < 8; ++j) {
        atomicAdd(out + (size_t)(bw + j) * 64 + lane, acc[j]);
    }
}

extern "C" void kernel_launch(void* const* d_in, const int* in_sizes, int n_in,
                              void* d_out, int out_size, void* d_ws, size_t ws_size,
                              hipStream_t stream) {
    const float* x      = (const float*)d_in[0];   // [8192, 64]
    const float* coeffs = (const float*)d_in[1];   // [64, 64, 64]
    const float* bias   = (const float*)d_in[2];   // [64]
    float* out = (float*)d_out;                    // [8192, 64]

    uint2* T = (uint2*)d_ws;                       // 2 MB table
    build_table<<<dim3(256), dim3(256), 0, stream>>>(coeffs, T, bias, out);
    kan_main<<<dim3(512), dim3(1024), 0, stream>>>(x, (const char*)T, out);
}

// Round 7
// 78.769 us; speedup vs baseline: 1.3608x; 1.3608x over previous
//
#include <hip/hip_runtime.h>
#include <hip/hip_fp16.h>
#include <stdint.h>

// ---------------------------------------------------------------------------
// BareKANLayer: out[b,o] = sum_d PCHIP_interp(x[b,d]; coeffs[o,d,:]) + bias[o]
// B=8192, O=64, D=64, K=64, grid [-2,2], h = 4/63.
//
// Table: per (d, interval i, o) cubic coeffs of p(u) = c0 + c1 u + c2 u^2 + c3 u^3
// packed as fp16 in a uint2: .x = (h(c1)<<16)|h(c0), .y = (h(c3)<<16)|h(c2).
// Row i=63 is a LINEAR row for right extrapolation. Left extrap = row 0, w2=w3=0.
// Layout: T[d][i][o], slice per d = 64*64*8 = 32 KB, total 2 MB in d_ws.
//
// Round-7 (= Round-6 with the compile fix): R4 structure (74.2 us, best) with
// ONE change: the table gather is a non-temporal load (nt policy bit).
// __builtin_nontemporal_load needs a native vector type, not HIP's uint4
// class -> use ext_vector_type(4) of uint.
// R4 analysis pinned kan_main at ~1 L1-sector fill per 4.4 cy/CU (268 MB
// random rows, 0% L1 hit — L1 allocation is pure overhead). nt = evict-first/
// no-allocate in L1; if the wall is allocation cost this streams from L2.
//   LDS-staging family abandoned after 3 failures (93.6/87.2/107.2 vs 74.2).
// ---------------------------------------------------------------------------

typedef _Float16 half2v __attribute__((ext_vector_type(2)));
typedef unsigned int uintv4 __attribute__((ext_vector_type(4)));

#if defined(__has_builtin)
#if __has_builtin(__builtin_amdgcn_fdot2)
#define HAS_FDOT2 1
#endif
#endif

__device__ __forceinline__ uint32_t h16(float f) {
    return (uint32_t)__half_as_ushort(__float2half(f));   // RNE cvt
}

__device__ __forceinline__ float dot2acc(uint32_t a_bits, uint32_t b_bits, float acc) {
    half2v a = __builtin_bit_cast(half2v, a_bits);
    half2v b = __builtin_bit_cast(half2v, b_bits);
#ifdef HAS_FDOT2
    return __builtin_amdgcn_fdot2(a, b, acc, false);
#else
    return acc + (float)a.x * (float)b.x + (float)a.y * (float)b.y;
#endif
}

// Grid: 256 blocks (d = bx>>2, o-quarter = bx&3), 256 threads.  (R0-identical)
__global__ void build_table(const float* __restrict__ coeffs, uint2* __restrict__ T) {
    const float hf = 4.0f / 63.0f;
    const float inv_hf = 63.0f / 4.0f;   // 15.75 exact in fp32
    int d  = blockIdx.x >> 2;
    int ob = (blockIdx.x & 3) << 4;      // base of this block's 16 o's
    __shared__ float Y[16][65];          // +1 pad: conflict-free
    int t = threadIdx.x;
    {
        int ol = t >> 4;                 // 0..15  (o local)
        int k4 = (t & 15) << 2;          // 0,4,...,60
        const float* src = coeffs + (size_t)(ob + ol) * 4096 + d * 64 + k4;
        float4 v = *(const float4*)src;  // 16B aligned
        Y[ol][k4 + 0] = v.x; Y[ol][k4 + 1] = v.y;
        Y[ol][k4 + 2] = v.z; Y[ol][k4 + 3] = v.w;
    }
    __syncthreads();
    for (int c = t; c < 1024; c += 256) {
        int ol = c & 15;
        int i  = c >> 4;                 // 0..63 (63 = linear extrapolation row)
        const float* Yr = Y[ol];
        auto delt = [&](int k) -> float { return (Yr[k + 1] - Yr[k]) * inv_hf; };
        auto endslope = [&](float a, float b) -> float {
            float de = (3.0f * a - b) * 0.5f;
            de = (de * a <= 0.0f) ? 0.0f : de;
            de = ((a * b < 0.0f) && (fabsf(de) > 3.0f * fabsf(a))) ? 3.0f * a : de;
            return de;
        };
        auto slope = [&](int k) -> float {
            if (k == 0)  return endslope(delt(0), delt(1));
            if (k == 63) return endslope(delt(62), delt(61));
            float dp = delt(k - 1), dn = delt(k);
            return (dp * dn > 0.0f) ? (2.0f * dp * dn) / (dp + dn + 1e-12f) : 0.0f;
        };
        uint2 pk;
        if (i < 63) {
            float y0 = Yr[i], y1 = Yr[i + 1];
            float di = slope(i), dj = slope(i + 1);
            float c0 = y0;
            float c1 = hf * di;
            float c2 = 3.0f * (y1 - y0) - hf * (2.0f * di + dj);
            float c3 = 2.0f * (y0 - y1) + hf * (di + dj);
            pk.x = (h16(c1) << 16) | h16(c0);
            pk.y = (h16(c3) << 16) | h16(c2);
        } else {
            float yN = Yr[63];
            float dN = slope(63);
            pk.x = (h16(hf * dN) << 16) | h16(yN);
            pk.y = 0u;
        }
        T[(size_t)d * 4096 + i * 64 + (ob + ol)] = pk;
    }
}

// Grid: 1024 blocks x 256 threads (4 waves). Wave wv serves b0 = bx*8+2wv,
// b1 = b0+1. Lane half h = lane>>5 -> b_h; ol = lane&31 -> o pair (2ol, 2ol+1).
__global__ void __launch_bounds__(256) kan_main(const float* __restrict__ x,
                                                const float* __restrict__ bias,
                                                const char* __restrict__ Tb,
                                                float* __restrict__ out) {
    __shared__ uint4 WL[8][64];          // 8 KB: records [b_local][d] (wave-private pairs)
    const int t     = threadIdx.x;
    const int lane  = t & 63;
    const int wv    = t >> 6;
    const int half  = lane >> 5;         // 0: b0, 1: b1
    const int ol    = lane & 31;         // o pair index
    const int bbase = blockIdx.x << 3;

    // ---- wave-private records: lane l builds (b0,d=l) and (b1,d=l) ----
    #pragma unroll
    for (int k = 0; k < 2; ++k) {
        int bl = (wv << 1) + k;
        float xv = x[(bbase + bl) * 64 + lane];
        float tt = (xv + 2.0f) * 15.75f;
        int i = (int)floorf(tt);
        i = i < 0 ? 0 : (i > 62 ? 62 : i);
        float u = tt - (float)i;
        float w1, w2, w3; uint32_t off;
        if (xv < -2.0f)      { w1 = tt;          w2 = 0.f;    w3 = 0.f;     off = 0u; }
        else if (xv > 2.0f)  { w1 = tt - 63.0f;  w2 = 0.f;    w3 = 0.f;     off = 63u << 9; }
        else                 { w1 = u;           w2 = u * u;  w3 = w2 * u;  off = (uint32_t)i << 9; }
        half2v wa; wa.x = (_Float16)1.0f; wa.y = (_Float16)w1;
        half2v wb; wb.x = (_Float16)w2;   wb.y = (_Float16)w3;
        WL[bl][lane] = make_uint4(__builtin_bit_cast(uint32_t, wa),
                                  __builtin_bit_cast(uint32_t, wb),
                                  ((uint32_t)lane << 15) | off, 0u);
    }
    // No __syncthreads: each wave reads only records it wrote (lgkmcnt orders).

    // ---- accumulate over d: one NT dwordx4 gather per lane (2 rows / wave) ----
    const uint4* rbase = &WL[(wv << 1) + half][0];
    const int laneoff = ol << 4;
    float ae0 = 0.0f, ae1 = 0.0f, ao0 = 0.0f, ao1 = 0.0f;
    #pragma unroll 8
    for (int d = 0; d < 64; ++d) {
        uint4 r = rbase[d];                              // 2-addr broadcast (free)
        uintv4 q = __builtin_nontemporal_load(
                       (const uintv4*)(Tb + r.z + laneoff));  // nt: no L1 alloc
        ae0 = dot2acc(r.x, q.x, ae0);                    // o even
        ae1 = dot2acc(r.y, q.y, ae1);
        ao0 = dot2acc(r.x, q.z, ao0);                    // o odd
        ao1 = dot2acc(r.y, q.w, ao1);
    }

    // ---- epilogue: lane writes o-pair of its b ----
    float2 bv = ((const float2*)bias)[ol];
    float2 res;
    res.x = ae0 + ae1 + bv.x;
    res.y = ao0 + ao1 + bv.y;
    int b = bbase + (wv << 1) + half;
    ((float2*)(out + (size_t)b * 64))[ol] = res;
}

extern "C" void kernel_launch(void* const* d_in, const int* in_sizes, int n_in,
                              void* d_out, int out_size, void* d_ws, size_t ws_size,
                              hipStream_t stream) {
    const float* x      = (const float*)d_in[0];   // [8192, 64]
    const float* coeffs = (const float*)d_in[1];   // [64, 64, 64]
    const float* bias   = (const float*)d_in[2];   // [64]
    float* out = (float*)d_out;                    // [8192, 64]

    uint2* T = (uint2*)d_ws;                       // 2 MB table
    build_table<<<dim3(256), dim3(256), 0, stream>>>(coeffs, T);
    kan_main<<<dim3(1024), dim3(256), 0, stream>>>(x, bias, (const char*)d_ws, out);
}

// Round 8
// 73.886 us; speedup vs baseline: 1.4508x; 1.0661x over previous
//
#include <hip/hip_runtime.h>
#include <hip/hip_fp16.h>
#include <stdint.h>

// ---------------------------------------------------------------------------
// BareKANLayer: out[b,o] = sum_d PCHIP_interp(x[b,d]; coeffs[o,d,:]) + bias[o]
// B=8192, O=64, D=64, K=64, grid [-2,2], h = 4/63.
//
// Table: per (d, interval i, o) cubic coeffs of p(u) = c0 + c1 u + c2 u^2 + c3 u^3
// packed as fp16 in a uint2: .x = (h(c1)<<16)|h(c0), .y = (h(c3)<<16)|h(c2).
// Row i=63 is a LINEAR row for right extrapolation. Left extrap = row 0, w2=w3=0.
// Layout: T[d][i][o], slice per d = 64*64*8 = 32 KB, total 2 MB in d_ws.
//
// FINAL (Round-8 = exact Round-4 revert, best measured 74.2 us):
//   dur = fill 42 (harness re-poison, 80% HBM roofline)
//       + build ~2.5
//       + main ~30 at the measured random-row wall (~15 B/cy/CU through
//         TCP/L2 for 268 MB of data-dependent 512 B rows).
// The wall was probed 5 ways, all null/negative: MLP x4 (R1), instr/2 with
// 16 B/lane max-width loads (R4, -5us issue share), LDS staging x3 (R2/R3/R5),
// occupancy 2->8 waves/SIMD (R5), nt no-L1-alloc (R7, +4.6us). Reorganizations
// (i-bucketing w/ LDS accumulators, one-hot MFMA, fp8 rows) are arithmetically
// bounded at/above the current floor or exceed the absmax tolerance.
// ---------------------------------------------------------------------------

typedef _Float16 half2v __attribute__((ext_vector_type(2)));

#if defined(__has_builtin)
#if __has_builtin(__builtin_amdgcn_fdot2)
#define HAS_FDOT2 1
#endif
#endif

__device__ __forceinline__ uint32_t h16(float f) {
    return (uint32_t)__half_as_ushort(__float2half(f));   // RNE cvt
}

__device__ __forceinline__ float dot2acc(uint32_t a_bits, uint32_t b_bits, float acc) {
    half2v a = __builtin_bit_cast(half2v, a_bits);
    half2v b = __builtin_bit_cast(half2v, b_bits);
#ifdef HAS_FDOT2
    return __builtin_amdgcn_fdot2(a, b, acc, false);
#else
    return acc + (float)a.x * (float)b.x + (float)a.y * (float)b.y;
#endif
}

// Grid: 256 blocks (d = bx>>2, o-quarter = bx&3), 256 threads.
__global__ void build_table(const float* __restrict__ coeffs, uint2* __restrict__ T) {
    const float hf = 4.0f / 63.0f;
    const float inv_hf = 63.0f / 4.0f;   // 15.75 exact in fp32
    int d  = blockIdx.x >> 2;
    int ob = (blockIdx.x & 3) << 4;      // base of this block's 16 o's
    __shared__ float Y[16][65];          // +1 pad: conflict-free
    int t = threadIdx.x;
    {
        int ol = t >> 4;                 // 0..15  (o local)
        int k4 = (t & 15) << 2;          // 0,4,...,60
        const float* src = coeffs + (size_t)(ob + ol) * 4096 + d * 64 + k4;
        float4 v = *(const float4*)src;  // 16B aligned
        Y[ol][k4 + 0] = v.x; Y[ol][k4 + 1] = v.y;
        Y[ol][k4 + 2] = v.z; Y[ol][k4 + 3] = v.w;
    }
    __syncthreads();
    for (int c = t; c < 1024; c += 256) {
        int ol = c & 15;
        int i  = c >> 4;                 // 0..63 (63 = linear extrapolation row)
        const float* Yr = Y[ol];
        auto delt = [&](int k) -> float { return (Yr[k + 1] - Yr[k]) * inv_hf; };
        auto endslope = [&](float a, float b) -> float {
            float de = (3.0f * a - b) * 0.5f;
            de = (de * a <= 0.0f) ? 0.0f : de;
            de = ((a * b < 0.0f) && (fabsf(de) > 3.0f * fabsf(a))) ? 3.0f * a : de;
            return de;
        };
        auto slope = [&](int k) -> float {
            if (k == 0)  return endslope(delt(0), delt(1));
            if (k == 63) return endslope(delt(62), delt(61));
            float dp = delt(k - 1), dn = delt(k);
            return (dp * dn > 0.0f) ? (2.0f * dp * dn) / (dp + dn + 1e-12f) : 0.0f;
        };
        uint2 pk;
        if (i < 63) {
            float y0 = Yr[i], y1 = Yr[i + 1];
            float di = slope(i), dj = slope(i + 1);
            float c0 = y0;
            float c1 = hf * di;
            float c2 = 3.0f * (y1 - y0) - hf * (2.0f * di + dj);
            float c3 = 2.0f * (y0 - y1) + hf * (di + dj);
            pk.x = (h16(c1) << 16) | h16(c0);
            pk.y = (h16(c3) << 16) | h16(c2);
        } else {
            float yN = Yr[63];
            float dN = slope(63);
            pk.x = (h16(hf * dN) << 16) | h16(yN);
            pk.y = 0u;
        }
        T[(size_t)d * 4096 + i * 64 + (ob + ol)] = pk;
    }
}

// Grid: 1024 blocks x 256 threads (4 waves). Wave wv serves b0 = bx*8+2wv,
// b1 = b0+1. Lane half h = lane>>5 -> b_h; ol = lane&31 -> o pair (2ol, 2ol+1).
__global__ void __launch_bounds__(256) kan_main(const float* __restrict__ x,
                                                const float* __restrict__ bias,
                                                const char* __restrict__ Tb,
                                                float* __restrict__ out) {
    __shared__ uint4 WL[8][64];          // 8 KB: records [b_local][d] (wave-private pairs)
    const int t     = threadIdx.x;
    const int lane  = t & 63;
    const int wv    = t >> 6;
    const int half  = lane >> 5;         // 0: b0, 1: b1
    const int ol    = lane & 31;         // o pair index
    const int bbase = blockIdx.x << 3;

    // ---- wave-private records: lane l builds (b0,d=l) and (b1,d=l) ----
    #pragma unroll
    for (int k = 0; k < 2; ++k) {
        int bl = (wv << 1) + k;
        float xv = x[(bbase + bl) * 64 + lane];
        float tt = (xv + 2.0f) * 15.75f;
        int i = (int)floorf(tt);
        i = i < 0 ? 0 : (i > 62 ? 62 : i);
        float u = tt - (float)i;
        float w1, w2, w3; uint32_t off;
        if (xv < -2.0f)      { w1 = tt;          w2 = 0.f;    w3 = 0.f;     off = 0u; }
        else if (xv > 2.0f)  { w1 = tt - 63.0f;  w2 = 0.f;    w3 = 0.f;     off = 63u << 9; }
        else                 { w1 = u;           w2 = u * u;  w3 = w2 * u;  off = (uint32_t)i << 9; }
        half2v wa; wa.x = (_Float16)1.0f; wa.y = (_Float16)w1;
        half2v wb; wb.x = (_Float16)w2;   wb.y = (_Float16)w3;
        WL[bl][lane] = make_uint4(__builtin_bit_cast(uint32_t, wa),
                                  __builtin_bit_cast(uint32_t, wb),
                                  ((uint32_t)lane << 15) | off, 0u);
    }
    // No __syncthreads: each wave reads only records it wrote (lgkmcnt orders).

    // ---- accumulate over d: one dwordx4 gather per lane (2 rows / wave) ----
    const uint4* rbase = &WL[(wv << 1) + half][0];
    const int laneoff = ol << 4;
    float ae0 = 0.0f, ae1 = 0.0f, ao0 = 0.0f, ao1 = 0.0f;
    #pragma unroll 8
    for (int d = 0; d < 64; ++d) {
        uint4 r = rbase[d];                              // 2-addr broadcast (free)
        uint4 q = *(const uint4*)(Tb + r.z + laneoff);   // 1KB/wave-instr, L2-hot
        ae0 = dot2acc(r.x, q.x, ae0);                    // o even
        ae1 = dot2acc(r.y, q.y, ae1);
        ao0 = dot2acc(r.x, q.z, ao0);                    // o odd
        ao1 = dot2acc(r.y, q.w, ao1);
    }

    // ---- epilogue: lane writes o-pair of its b ----
    float2 bv = ((const float2*)bias)[ol];
    float2 res;
    res.x = ae0 + ae1 + bv.x;
    res.y = ao0 + ao1 + bv.y;
    int b = bbase + (wv << 1) + half;
    ((float2*)(out + (size_t)b * 64))[ol] = res;
}

extern "C" void kernel_launch(void* const* d_in, const int* in_sizes, int n_in,
                              void* d_out, int out_size, void* d_ws, size_t ws_size,
                              hipStream_t stream) {
    const float* x      = (const float*)d_in[0];   // [8192, 64]
    const float* coeffs = (const float*)d_in[1];   // [64, 64, 64]
    const float* bias   = (const float*)d_in[2];   // [64]
    float* out = (float*)d_out;                    // [8192, 64]

    uint2* T = (uint2*)d_ws;                       // 2 MB table
    build_table<<<dim3(256), dim3(256), 0, stream>>>(coeffs, T);
    kan_main<<<dim3(1024), dim3(256), 0, stream>>>(x, bias, (const char*)d_ws, out);
}